// Round 13
// baseline (2669.773 us; speedup 1.0000x reference)
//
#include <hip/hip_runtime.h>
#include <hip/hip_bf16.h>
#include <hip/hip_fp16.h>

typedef _Float16 f16;
typedef _Float16 f16x8 __attribute__((ext_vector_type(8)));
typedef float f32x16 __attribute__((ext_vector_type(16)));
typedef unsigned int u32;

// Problem sizes (fixed)
#define BB 32
#define SS 2048
#define HH 1024
#define KK 1024

// ws layout (bytes)
#define WS_BP 0                            // packed Wv fp16: 2 MB
#define WS_HQ (2u*1024u*1024u)             // hq fp32: 32*1024*4 = 128 KB
#define WS_LP (WS_HQ + 131072u)            // logits partials: 4*32*2048*4 = 1 MB

__device__ __forceinline__ float tanh_f(float x) {
    // tanh(x) = 1 - 2/(e^{2x}+1); safe at +/-inf of exp
    float e = __expf(2.0f * x);
    return 1.0f - 2.0f * __builtin_amdgcn_rcpf(e + 1.0f);
}

// fp32x8 -> fp16x8 cvt + 16B LDS store
__device__ __forceinline__ void write_a16(char* dst, int off, float4 va, float4 vb) {
    union { f16 h[8]; uint4 u; } pk;
    pk.h[0] = (f16)va.x; pk.h[1] = (f16)va.y; pk.h[2] = (f16)va.z; pk.h[3] = (f16)va.w;
    pk.h[4] = (f16)vb.x; pk.h[5] = (f16)vb.y; pk.h[6] = (f16)vb.z; pk.h[7] = (f16)vb.w;
    *(uint4*)(dst + off) = pk.u;
}

// ---------------------------------------------------------------------------
// Pack Wv [k][n] fp32 -> fragment-ordered fp16 for mfma_f32_32x32x16_f16 B.
// Layout: BP[ntb(4)][kit(16)][wc(4)][ks(4)][ntl(2)][lane(64)][j(8)]
//   n = ntb*256 + wc*64 + ntl*32 + (lane&31); k = kit*64 + ks*16 + (lane>>5)*8 + j
// Per (block, wave): per BK=32 epoch e, one contiguous 4 KB chunk at
//   ntb*524288 + wc*8192 + (e>>1)*32768 + (e&1)*4096.
__global__ void pack_wv(const float* __restrict__ Wv, f16* __restrict__ BP) {
    int i = blockIdx.x * 256 + threadIdx.x;   // i = k*1024 + n
    int k = i >> 10, n = i & 1023;
    float v = Wv[i];
    int ntb = n >> 8, wc = (n >> 6) & 3, ntl = (n >> 5) & 1, nl = n & 31;
    int kit = k >> 6, ks = (k >> 4) & 3, lg = (k >> 3) & 1, j = k & 7;
    int lane = lg * 32 + nl;
    BP[((((((ntb * 16 + kit) * 4 + wc) * 4 + ks) * 2 + ntl) * 64 + lane) * 8) + j] = (f16)v;
}

// ---------------------------------------------------------------------------
// hq = query @ Wq + bq  (fp32). K split 4 ways, atomicAdd combine.
__global__ void hq_kernel(const float* __restrict__ query, const float* __restrict__ Wq,
                          const float* __restrict__ bq, float* __restrict__ hq) {
    int b = blockIdx.y;
    int h = (blockIdx.x & 3) * 256 + threadIdx.x;
    int v0 = (blockIdx.x >> 2) * 256;
    float acc = 0.f;
#pragma unroll 8
    for (int v = 0; v < 256; ++v)
        acc += query[b * 1024 + v0 + v] * Wq[(v0 + v) * 1024 + h];
    if (v0 == 0) acc += bq[h];
    atomicAdd(&hq[b * 1024 + h], acc);
}

// ---------------------------------------------------------------------------
// Fused 128x256x(K=1024) GEMM tile + tanh(hq+hv)·w row-reduction.
// Round 12 minus the spill: A staging is the round-11 1-epoch scheme (load
// A(e+1) into ONE float4 pair at the top of epoch e, cvt+write at epoch end
// -- 8 regs, not 16), keeping round-8's B discipline (reg double buffer
// loaded one FULL epoch ahead of use). Budget: acc 64 + bvA/bvB 32 + ar 8
// + transients ~16 <= 128 cap -> no scratch (WRITE_SIZE is the check).
// BK=32 epochs, lgkm(0)+raw barrier per epoch, vmcnt never drained at
// barriers. 8 waves (2wr x 4wc), wave tile 64x64, 2 blocks/CU.
__launch_bounds__(512, 4)
__global__ void fused_main(const float* __restrict__ value, const f16* __restrict__ BP,
                           const float* __restrict__ hq, const float* __restrict__ wvec,
                           float* __restrict__ lpart) {
    extern __shared__ char smem[];             // 16 KB: A0 [0,8K), A1 [8K,16K)
    char* A0 = smem;
    char* A1 = smem + 8192;

    int bid = blockIdx.x;
    int tile = (bid & 7) * 256 + (bid >> 3);   // XCD swizzle; 4 ntb of one Mt co-XCD
    int Mt = tile >> 2, ntb = tile & 3;
    int m0 = Mt << 7;                          // 128 rows
    int b = m0 >> 11, s0 = m0 & 2047;

    int tid = threadIdx.x;
    int w = tid >> 6, l = tid & 63;
    int wr = w >> 2, wc = w & 3;
    int l31 = l & 31, lg = l >> 5;

    // ---- A staging: thread covers row tid>>2 (0..127), 8 floats at (tid&3)*8
    int arow = tid >> 2;
    const float* aga = value + (size_t)(m0 + arow) * 1024 + (tid & 3) * 8;
    // frag slot: [mtb(4)=row>>5][ks(2)=(k>>4)][lane=lg*32+row31][j=k&7], one b128
    int aw = ((arow >> 5) * 2 + ((tid & 3) >> 1)) * 1024
           + (((tid & 1) << 5) + (arow & 31)) * 16;

    // ---- B per-wave base; epoch e chunk (4 KB) at +(e>>1)*32768 + (e&1)*4096
    const char* bg = (const char*)BP + (size_t)ntb * 524288 + (size_t)wc * 8192
                   + (size_t)l * 16;

    // ---- A frag read offsets (conflict-free lane*16), + ks*1024 per slice
    int a_off0 = (wr * 2 + 0) * 2048 + l * 16;
    int a_off1 = (wr * 2 + 1) * 2048 + l * 16;

    const f32x16 fzero = {};
    f32x16 acc[2][2];
#pragma unroll
    for (int mt = 0; mt < 2; ++mt)
#pragma unroll
        for (int nt = 0; nt < 2; ++nt) acc[mt][nt] = fzero;

    f16x8 bvA[4], bvB[4];                      // B reg double buffer (1 epoch ahead)
    float4 ar0, ar1;                           // A staging pair (1-epoch scheme)

#define COMPUTE(Ab, BV) do { \
        f16x8 a00 = *(const f16x8*)((Ab) + a_off0); \
        f16x8 a10 = *(const f16x8*)((Ab) + a_off1); \
        f16x8 a01 = *(const f16x8*)((Ab) + a_off0 + 1024); \
        f16x8 a11 = *(const f16x8*)((Ab) + a_off1 + 1024); \
        __builtin_amdgcn_s_setprio(1); \
        acc[0][0] = __builtin_amdgcn_mfma_f32_32x32x16_f16(a00, (BV)[0], acc[0][0], 0, 0, 0); \
        acc[0][1] = __builtin_amdgcn_mfma_f32_32x32x16_f16(a00, (BV)[1], acc[0][1], 0, 0, 0); \
        acc[1][0] = __builtin_amdgcn_mfma_f32_32x32x16_f16(a10, (BV)[0], acc[1][0], 0, 0, 0); \
        acc[1][1] = __builtin_amdgcn_mfma_f32_32x32x16_f16(a10, (BV)[1], acc[1][1], 0, 0, 0); \
        acc[0][0] = __builtin_amdgcn_mfma_f32_32x32x16_f16(a01, (BV)[2], acc[0][0], 0, 0, 0); \
        acc[0][1] = __builtin_amdgcn_mfma_f32_32x32x16_f16(a01, (BV)[3], acc[0][1], 0, 0, 0); \
        acc[1][0] = __builtin_amdgcn_mfma_f32_32x32x16_f16(a11, (BV)[2], acc[1][0], 0, 0, 0); \
        acc[1][1] = __builtin_amdgcn_mfma_f32_32x32x16_f16(a11, (BV)[3], acc[1][1], 0, 0, 0); \
        __builtin_amdgcn_s_setprio(0); \
    } while (0)

#define LOADB(BV, e) do { \
        const char* bt_ = bg + (size_t)((e) >> 1) * 32768 + ((e) & 1) * 4096; \
        (BV)[0] = *(const f16x8*)(bt_); \
        (BV)[1] = *(const f16x8*)(bt_ + 1024); \
        (BV)[2] = *(const f16x8*)(bt_ + 2048); \
        (BV)[3] = *(const f16x8*)(bt_ + 3072); \
    } while (0)

    // ---- prologue: A(0) -> A0 LDS; B(0) -> bvA
    {
        const float4* ap = (const float4*)aga;
        float4 p0 = ap[0], p1 = ap[1];
        write_a16(A0, aw, p0, p1);
        LOADB(bvA, 0);
        asm volatile("s_waitcnt lgkmcnt(0)" ::: "memory");
        __builtin_amdgcn_s_barrier();
    }

    // ---- main loop: 32 epochs of BK=32 as 16 x (even/odd); barriers carry
    // NO vmcnt — A/B global loads always have ~1 full epoch of cover.
#pragma unroll 1
    for (int tt = 0; tt < 16; ++tt) {
        {   // even e = 2tt: compute (A0, bvA); prefetch B(e+1)->bvB; A(e+1)->ar
            LOADB(bvB, 2 * tt + 1);
            const float4* ap = (const float4*)(aga + (2 * tt + 1) * 32);
            ar0 = ap[0]; ar1 = ap[1];
            COMPUTE(A0, bvA);
            write_a16(A1, aw, ar0, ar1);           // A(e+1), full epoch of cover
            asm volatile("s_waitcnt lgkmcnt(0)" ::: "memory");
            __builtin_amdgcn_s_barrier();
        }
        {   // odd e = 2tt+1: compute (A1, bvB); prefetch B(e+1)->bvA; A(e+1)->ar
            if (tt < 15) {
                LOADB(bvA, 2 * tt + 2);
                const float4* ap = (const float4*)(aga + (2 * tt + 2) * 32);
                ar0 = ap[0]; ar1 = ap[1];
                COMPUTE(A1, bvB);
                write_a16(A0, aw, ar0, ar1);       // A(2tt+2)
            } else {
                COMPUTE(A1, bvB);                  // last epoch: no staging
            }
            asm volatile("s_waitcnt lgkmcnt(0)" ::: "memory");
            __builtin_amdgcn_s_barrier();
        }
    }
#undef COMPUTE
#undef LOADB

    // ---- epilogue: t = tanh(hq + hv) * w, pair-folded col reduction
    int h0 = ntb * 256 + wc * 64 + l31;   // nt = 0
    int h1 = h0 + 32;                     // nt = 1
    float hq0 = hq[b * 1024 + h0], hq1 = hq[b * 1024 + h1];
    float w0 = wvec[h0], w1 = wvec[h1];

    float* part = (float*)smem;           // 2 KB [wc(4)][row(128)]; A dead now
#pragma unroll
    for (int mt = 0; mt < 2; ++mt) {
#pragma unroll
        for (int i = 0; i < 8; ++i) {
            float pa = tanh_f(hq0 + acc[mt][0][2 * i]) * w0
                     + tanh_f(hq1 + acc[mt][1][2 * i]) * w1;
            float pb = tanh_f(hq0 + acc[mt][0][2 * i + 1]) * w0
                     + tanh_f(hq1 + acc[mt][1][2 * i + 1]) * w1;
            float ea = __shfl_xor(pa, 1), eb = __shfl_xor(pb, 1);
            float g = (l & 1) ? (pb + eb) : (pa + ea);
            g += __shfl_xor(g, 2); g += __shfl_xor(g, 4);
            g += __shfl_xor(g, 8); g += __shfl_xor(g, 16);
            if (l31 < 2) {
                int r = 2 * i + (l31 & 1);
                int row = wr * 64 + mt * 32 + (r & 3) + ((r >> 2) << 3) + (lg << 2);
                part[wc * 128 + row] = g;
            }
        }
    }
    __syncthreads();
    if (tid < 128) {
        float s = part[tid] + part[128 + tid] + part[256 + tid] + part[384 + tid];
        lpart[((size_t)ntb * 32 + b) * 2048 + s0 + tid] = s;
    }
}

// ---------------------------------------------------------------------------
// Masked softmax over S=2048 per b, summing the 4 N-block logit partials.
__global__ void softmax_kernel(const float* __restrict__ lp, const int* __restrict__ mask,
                               float* __restrict__ out) {
    __shared__ float redm[16];
    __shared__ float reds[16];
    const int P = 32 * 2048;
    int b = blockIdx.x, t = threadIdx.x;
    int wid = t >> 6, lane = t & 63;
    int i0 = b * 2048 + t, i1 = i0 + 1024;
    float l0 = lp[i0] + lp[P + i0] + lp[2 * P + i0] + lp[3 * P + i0];
    float l1 = lp[i1] + lp[P + i1] + lp[2 * P + i1] + lp[3 * P + i1];
    float a0 = mask[i0] ? l0 : -1e9f;
    float a1 = mask[i1] ? l1 : -1e9f;
    float mx = fmaxf(a0, a1);
#pragma unroll
    for (int off = 1; off < 64; off <<= 1) mx = fmaxf(mx, __shfl_xor(mx, off));
    if (lane == 0) redm[wid] = mx;
    __syncthreads();
    mx = redm[0];
#pragma unroll
    for (int i = 1; i < 16; ++i) mx = fmaxf(mx, redm[i]);
    float e0 = __expf(a0 - mx), e1 = __expf(a1 - mx);
    float s = e0 + e1;
#pragma unroll
    for (int off = 1; off < 64; off <<= 1) s += __shfl_xor(s, off);
    if (lane == 0) reds[wid] = s;
    __syncthreads();
    float tot = 0.f;
#pragma unroll
    for (int i = 0; i < 16; ++i) tot += reds[i];
    float inv = 1.0f / tot;
    out[b * 2048 + t] = e0 * inv;
    out[b * 2048 + 1024 + t] = e1 * inv;
}

// ---------------------------------------------------------------------------
extern "C" void kernel_launch(void* const* d_in, const int* in_sizes, int n_in,
                              void* d_out, int out_size, void* d_ws, size_t ws_size,
                              hipStream_t stream) {
    const float* query = (const float*)d_in[0];
    const float* value = (const float*)d_in[1];
    const int*   mask  = (const int*)d_in[2];
    const float* Wq    = (const float*)d_in[3];
    const float* bq    = (const float*)d_in[4];
    const float* Wv    = (const float*)d_in[5];
    const float* wv    = (const float*)d_in[6];

    char* ws = (char*)d_ws;
    f16*   BP    = (f16*)(ws + WS_BP);
    float* hq    = (float*)(ws + WS_HQ);
    float* lpart = (float*)(ws + WS_LP);
    float* out   = (float*)d_out;

    (void)hipMemsetAsync(hq, 0, BB * HH * sizeof(float), stream);
    pack_wv<<<(KK * HH) / 256, 256, 0, stream>>>(Wv, BP);
    hq_kernel<<<dim3(16, BB), 256, 0, stream>>>(query, Wq, bq, hq);
    fused_main<<<2048, 512, 16384, stream>>>(value, BP, hq, wv, lpart);
    softmax_kernel<<<BB, 1024, 0, stream>>>(lpart, mask, out);
}

// Round 14
// 223.642 us; speedup vs baseline: 11.9377x; 11.9377x over previous
//
#include <hip/hip_runtime.h>
#include <hip/hip_bf16.h>
#include <hip/hip_fp16.h>

typedef _Float16 f16;
typedef _Float16 f16x8 __attribute__((ext_vector_type(8)));
typedef float f32x16 __attribute__((ext_vector_type(16)));
typedef unsigned int u32;

// Problem sizes (fixed)
#define BB 32
#define SS 2048
#define HH 1024
#define KK 1024

// ws layout (bytes)
#define WS_BP 0                            // packed Wv fp16: 2 MB
#define WS_HQ (2u*1024u*1024u)             // hq fp32: 32*1024*4 = 128 KB
#define WS_LP (WS_HQ + 131072u)            // logits partials: 4*32*2048*4 = 1 MB

__device__ __forceinline__ float tanh_f(float x) {
    // tanh(x) = 1 - 2/(e^{2x}+1); safe at +/-inf of exp
    float e = __expf(2.0f * x);
    return 1.0f - 2.0f * __builtin_amdgcn_rcpf(e + 1.0f);
}

// fp32x8 -> fp16x8 cvt + 16B LDS store
__device__ __forceinline__ void write_a16(char* dst, int off, float4 va, float4 vb) {
    union { f16 h[8]; uint4 u; } pk;
    pk.h[0] = (f16)va.x; pk.h[1] = (f16)va.y; pk.h[2] = (f16)va.z; pk.h[3] = (f16)va.w;
    pk.h[4] = (f16)vb.x; pk.h[5] = (f16)vb.y; pk.h[6] = (f16)vb.z; pk.h[7] = (f16)vb.w;
    *(uint4*)(dst + off) = pk.u;
}

// ---------------------------------------------------------------------------
// Pack Wv [k][n] fp32 -> fragment-ordered fp16 for mfma_f32_32x32x16_f16 B.
// Layout: BP[ntb(4)][kit(32)][wc(4)][ks(2)][ntl(2)][lane(64)][j(8)]
//   n = ntb*256 + wc*64 + ntl*32 + (lane&31); k = kit*32 + ks*16 + (lane>>5)*8 + j
// Per (ntb, epoch kit, wave wc): ONE contiguous 4 KB chunk (4 x 1KB frags).
__global__ void pack_wv(const float* __restrict__ Wv, f16* __restrict__ BP) {
    int i = blockIdx.x * 256 + threadIdx.x;   // i = k*1024 + n
    int k = i >> 10, n = i & 1023;
    float v = Wv[i];
    int ntb = n >> 8, wc = (n >> 6) & 3, ntl = (n >> 5) & 1, nl = n & 31;
    int kit = k >> 5, ks = (k >> 4) & 1, lg = (k >> 3) & 1, j = k & 7;
    int lane = lg * 32 + nl;
    BP[((((((ntb * 32 + kit) * 4 + wc) * 2 + ks) * 2 + ntl) * 64 + lane) * 8) + j] = (f16)v;
}

// ---------------------------------------------------------------------------
// hq = query @ Wq + bq  (fp32). K split 4 ways, atomicAdd combine.
__global__ void hq_kernel(const float* __restrict__ query, const float* __restrict__ Wq,
                          const float* __restrict__ bq, float* __restrict__ hq) {
    int b = blockIdx.y;
    int h = (blockIdx.x & 3) * 256 + threadIdx.x;
    int v0 = (blockIdx.x >> 2) * 256;
    float acc = 0.f;
#pragma unroll 8
    for (int v = 0; v < 256; ++v)
        acc += query[b * 1024 + v0 + v] * Wq[(v0 + v) * 1024 + h];
    if (v0 == 0) acc += bq[h];
    atomicAdd(&hq[b * 1024 + h], acc);
}

// ---------------------------------------------------------------------------
// Fused 64x256x(K=1024) GEMM tile + tanh(hq+hv)·w row-reduction.
// Round-8's proven pipeline skeleton (B reg double-buffer loaded ONE FULL
// EPOCH ahead; A 2-deep register pipeline fe/fo; frag-ordered static LDS A
// dbuf 2x4KB; lgkm(0)+raw barrier per epoch; vmcnt NEVER drained) at the
// m97 residency regime: 256-thread/4-wave blocks, launch_bounds(256,3) ->
// 170-VGPR ceiling (acc 64 + B 32 + A 16 + transients ~16 + addr ~12 = ~140,
// NO spill) and 3 INDEPENDENT blocks/CU whose unsynchronized barrier groups
// cover each other's drains. Wave wc owns cols wc*64..wc*64+64 (2 ntl frags).
__launch_bounds__(256, 3)
__global__ void fused_main(const float* __restrict__ value, const f16* __restrict__ BP,
                           const float* __restrict__ hq, const float* __restrict__ wvec,
                           float* __restrict__ lpart) {
    __shared__ char A0[4096];                  // frag-ordered [mt(2)][ks(2)][lane][j]
    __shared__ char A1[4096];
    __shared__ float part[256];                // [wc(4)][row(64)]

    int bid = blockIdx.x;
    int tile = (bid & 7) * 512 + (bid >> 3);   // XCD swizzle (4096 % 8 == 0)
    int Mt = tile >> 2, ntb = tile & 3;        // 4 ntb of one Mt co-XCD
    int m0 = Mt << 6;                          // 64 rows
    int b = m0 >> 11, s0 = m0 & 2047;

    int tid = threadIdx.x;
    int wc = tid >> 6, l = tid & 63;
    int l31 = l & 31, lg = l >> 5;

    // ---- A staging: thread covers row tid>>2 (0..63), 8 floats at (tid&3)*8
    int arow = tid >> 2;
    const float* aga = value + (size_t)(m0 + arow) * 1024 + (tid & 3) * 8;
    // frag slot: [mt=row>>5][ks=(k0>>4)][lane=((k0>>3)&1)*32 + row31][j], 16B
    int aw = ((arow >> 5) * 2 + ((tid & 3) >> 1)) * 1024
           + ((((tid & 3) & 1) << 5) + (arow & 31)) * 16;

    // ---- B per-wave base; epoch e chunk (4 KB) at + e*16384
    const char* bg = (const char*)BP + (size_t)ntb * 524288 + (size_t)wc * 4096
                   + (size_t)l * 16;

    // ---- A frag read offsets (conflict-free lane*16): mt at *2048, ks at *1024
    int a_off0 = l * 16;                       // mt = 0
    int a_off1 = 2048 + l * 16;                // mt = 1

    const f32x16 fzero = {};
    f32x16 acc[2][2];
#pragma unroll
    for (int mt = 0; mt < 2; ++mt)
#pragma unroll
        for (int nt = 0; nt < 2; ++nt) acc[mt][nt] = fzero;

    f16x8 bvA[4], bvB[4];                      // B reg double buffer (1 epoch ahead)
    float4 fe0, fe1, fo0, fo1;                 // A 2-deep reg pipeline

#define COMPUTE(Ab, BV) do { \
        f16x8 a00 = *(const f16x8*)((Ab) + a_off0); \
        f16x8 a10 = *(const f16x8*)((Ab) + a_off1); \
        f16x8 a01 = *(const f16x8*)((Ab) + a_off0 + 1024); \
        f16x8 a11 = *(const f16x8*)((Ab) + a_off1 + 1024); \
        __builtin_amdgcn_s_setprio(1); \
        acc[0][0] = __builtin_amdgcn_mfma_f32_32x32x16_f16(a00, (BV)[0], acc[0][0], 0, 0, 0); \
        acc[0][1] = __builtin_amdgcn_mfma_f32_32x32x16_f16(a00, (BV)[1], acc[0][1], 0, 0, 0); \
        acc[1][0] = __builtin_amdgcn_mfma_f32_32x32x16_f16(a10, (BV)[0], acc[1][0], 0, 0, 0); \
        acc[1][1] = __builtin_amdgcn_mfma_f32_32x32x16_f16(a10, (BV)[1], acc[1][1], 0, 0, 0); \
        acc[0][0] = __builtin_amdgcn_mfma_f32_32x32x16_f16(a01, (BV)[2], acc[0][0], 0, 0, 0); \
        acc[0][1] = __builtin_amdgcn_mfma_f32_32x32x16_f16(a01, (BV)[3], acc[0][1], 0, 0, 0); \
        acc[1][0] = __builtin_amdgcn_mfma_f32_32x32x16_f16(a11, (BV)[2], acc[1][0], 0, 0, 0); \
        acc[1][1] = __builtin_amdgcn_mfma_f32_32x32x16_f16(a11, (BV)[3], acc[1][1], 0, 0, 0); \
        __builtin_amdgcn_s_setprio(0); \
    } while (0)

#define LOADB(BV, e) do { \
        const char* bt_ = bg + (size_t)(e) * 16384; \
        (BV)[0] = *(const f16x8*)(bt_); \
        (BV)[1] = *(const f16x8*)(bt_ + 1024); \
        (BV)[2] = *(const f16x8*)(bt_ + 2048); \
        (BV)[3] = *(const f16x8*)(bt_ + 3072); \
    } while (0)

    // ---- prologue: A(0)->A0; A(1)->fo; B(0)->bvA
    {
        const float4* ap = (const float4*)aga;
        float4 p0 = ap[0], p1 = ap[1];
        write_a16(A0, aw, p0, p1);
        const float4* ap1 = (const float4*)(aga + 32);
        fo0 = ap1[0]; fo1 = ap1[1];
        LOADB(bvA, 0);
        asm volatile("s_waitcnt lgkmcnt(0)" ::: "memory");
        __builtin_amdgcn_s_barrier();
    }

    // ---- main loop: 32 epochs of BK=32 as 16 x (even/odd); barriers carry
    // NO vmcnt — A/B global loads always have >= 1 full epoch of cover.
#pragma unroll 1
    for (int tt = 0; tt < 16; ++tt) {
        {   // even e = 2tt: compute (A0, bvA); prefetch B(e+1)->bvB, A(e+2)->fe
            LOADB(bvB, 2 * tt + 1);
            int xa = 2 * tt + 2; if (xa > 31) xa = 31;   // clamped dummy at tail
            const float4* ap = (const float4*)(aga + xa * 32);
            fe0 = ap[0]; fe1 = ap[1];
            COMPUTE(A0, bvA);
            write_a16(A1, aw, fo0, fo1);           // A(e+1), loaded 1 epoch ago
            asm volatile("s_waitcnt lgkmcnt(0)" ::: "memory");
            __builtin_amdgcn_s_barrier();
        }
        {   // odd e = 2tt+1: compute (A1, bvB); prefetch B(e+2)->bvA, A(e+2)->fo
            int xb = 2 * tt + 2; if (xb > 31) xb = 31;
            LOADB(bvA, xb);
            int xc = 2 * tt + 3; if (xc > 31) xc = 31;
            const float4* ap = (const float4*)(aga + xc * 32);
            fo0 = ap[0]; fo1 = ap[1];
            COMPUTE(A1, bvB);
            if (tt < 15) write_a16(A0, aw, fe0, fe1);   // A(2tt+2)
            asm volatile("s_waitcnt lgkmcnt(0)" ::: "memory");
            __builtin_amdgcn_s_barrier();
        }
    }
#undef COMPUTE
#undef LOADB

    // ---- epilogue: t = tanh(hq + hv) * w, pair-folded col reduction
    int h0 = ntb * 256 + wc * 64 + l31;   // ntl = 0
    int h1 = h0 + 32;                     // ntl = 1
    float hq0 = hq[b * 1024 + h0], hq1 = hq[b * 1024 + h1];
    float w0 = wvec[h0], w1 = wvec[h1];

#pragma unroll
    for (int mt = 0; mt < 2; ++mt) {
#pragma unroll
        for (int i = 0; i < 8; ++i) {
            float pa = tanh_f(hq0 + acc[mt][0][2 * i]) * w0
                     + tanh_f(hq1 + acc[mt][1][2 * i]) * w1;
            float pb = tanh_f(hq0 + acc[mt][0][2 * i + 1]) * w0
                     + tanh_f(hq1 + acc[mt][1][2 * i + 1]) * w1;
            float ea = __shfl_xor(pa, 1), eb = __shfl_xor(pb, 1);
            float g = (l & 1) ? (pb + eb) : (pa + ea);
            g += __shfl_xor(g, 2); g += __shfl_xor(g, 4);
            g += __shfl_xor(g, 8); g += __shfl_xor(g, 16);
            if (l31 < 2) {
                int r = 2 * i + (l31 & 1);
                int row = mt * 32 + (r & 3) + ((r >> 2) << 3) + (lg << 2);
                part[wc * 64 + row] = g;
            }
        }
    }
    __syncthreads();
    if (tid < 64) {
        float s = part[tid] + part[64 + tid] + part[128 + tid] + part[192 + tid];
        lpart[((size_t)ntb * 32 + b) * 2048 + s0 + tid] = s;
    }
}

// ---------------------------------------------------------------------------
// Masked softmax over S=2048 per b, summing the 4 N-block logit partials.
__global__ void softmax_kernel(const float* __restrict__ lp, const int* __restrict__ mask,
                               float* __restrict__ out) {
    __shared__ float redm[16];
    __shared__ float reds[16];
    const int P = 32 * 2048;
    int b = blockIdx.x, t = threadIdx.x;
    int wid = t >> 6, lane = t & 63;
    int i0 = b * 2048 + t, i1 = i0 + 1024;
    float l0 = lp[i0] + lp[P + i0] + lp[2 * P + i0] + lp[3 * P + i0];
    float l1 = lp[i1] + lp[P + i1] + lp[2 * P + i1] + lp[3 * P + i1];
    float a0 = mask[i0] ? l0 : -1e9f;
    float a1 = mask[i1] ? l1 : -1e9f;
    float mx = fmaxf(a0, a1);
#pragma unroll
    for (int off = 1; off < 64; off <<= 1) mx = fmaxf(mx, __shfl_xor(mx, off));
    if (lane == 0) redm[wid] = mx;
    __syncthreads();
    mx = redm[0];
#pragma unroll
    for (int i = 1; i < 16; ++i) mx = fmaxf(mx, redm[i]);
    float e0 = __expf(a0 - mx), e1 = __expf(a1 - mx);
    float s = e0 + e1;
#pragma unroll
    for (int off = 1; off < 64; off <<= 1) s += __shfl_xor(s, off);
    if (lane == 0) reds[wid] = s;
    __syncthreads();
    float tot = 0.f;
#pragma unroll
    for (int i = 0; i < 16; ++i) tot += reds[i];
    float inv = 1.0f / tot;
    out[b * 2048 + t] = e0 * inv;
    out[b * 2048 + 1024 + t] = e1 * inv;
}

// ---------------------------------------------------------------------------
extern "C" void kernel_launch(void* const* d_in, const int* in_sizes, int n_in,
                              void* d_out, int out_size, void* d_ws, size_t ws_size,
                              hipStream_t stream) {
    const float* query = (const float*)d_in[0];
    const float* value = (const float*)d_in[1];
    const int*   mask  = (const int*)d_in[2];
    const float* Wq    = (const float*)d_in[3];
    const float* bq    = (const float*)d_in[4];
    const float* Wv    = (const float*)d_in[5];
    const float* wv    = (const float*)d_in[6];

    char* ws = (char*)d_ws;
    f16*   BP    = (f16*)(ws + WS_BP);
    float* hq    = (float*)(ws + WS_HQ);
    float* lpart = (float*)(ws + WS_LP);
    float* out   = (float*)d_out;

    (void)hipMemsetAsync(hq, 0, BB * HH * sizeof(float), stream);
    pack_wv<<<(KK * HH) / 256, 256, 0, stream>>>(Wv, BP);
    hq_kernel<<<dim3(16, BB), 256, 0, stream>>>(query, Wq, bq, hq);
    fused_main<<<4096, 256, 0, stream>>>(value, BP, hq, wv, lpart);
    softmax_kernel<<<BB, 1024, 0, stream>>>(lpart, mask, out);
}

// Round 15
// 221.237 us; speedup vs baseline: 12.0675x; 1.0109x over previous
//
#include <hip/hip_runtime.h>
#include <hip/hip_bf16.h>
#include <hip/hip_fp16.h>

typedef _Float16 f16;
typedef _Float16 f16x8 __attribute__((ext_vector_type(8)));
typedef float f32x16 __attribute__((ext_vector_type(16)));
typedef unsigned int u32;

// Problem sizes (fixed)
#define BB 32
#define SS 2048
#define HH 1024
#define KK 1024

// ws layout (bytes)
#define WS_BP 0                            // packed Wv fp16: 2 MB
#define WS_HQ (2u*1024u*1024u)             // hq fp32: 32*1024*4 = 128 KB
#define WS_LP (WS_HQ + 131072u)            // logits partials: 4*32*2048*4 = 1 MB

__device__ __forceinline__ float tanh_f(float x) {
    // tanh(x) = 1 - 2/(e^{2x}+1); safe at +/-inf of exp
    float e = __expf(2.0f * x);
    return 1.0f - 2.0f * __builtin_amdgcn_rcpf(e + 1.0f);
}

// fp32x8 -> fp16x8 cvt + 16B LDS store
__device__ __forceinline__ void write_a16(char* dst, int off, float4 va, float4 vb) {
    union { f16 h[8]; uint4 u; } pk;
    pk.h[0] = (f16)va.x; pk.h[1] = (f16)va.y; pk.h[2] = (f16)va.z; pk.h[3] = (f16)va.w;
    pk.h[4] = (f16)vb.x; pk.h[5] = (f16)vb.y; pk.h[6] = (f16)vb.z; pk.h[7] = (f16)vb.w;
    *(uint4*)(dst + off) = pk.u;
}

// ---------------------------------------------------------------------------
// Pack Wv [k][n] fp32 -> fragment-ordered fp16 for mfma_f32_32x32x16_f16 B.
// Layout: BP[ntb(4)][kit(16)][wc(4)][ks(4)][ntl(2)][lane(64)][j(8)]
//   n = ntb*256 + wc*64 + ntl*32 + (lane&31); k = kit*64 + ks*16 + (lane>>5)*8 + j
// Per (block, wave, BK=64 epoch): ONE contiguous 8 KB chunk; ks01 half at +0,
// ks23 half at +4096.
__global__ void pack_wv(const float* __restrict__ Wv, f16* __restrict__ BP) {
    int i = blockIdx.x * 256 + threadIdx.x;   // i = k*1024 + n
    int k = i >> 10, n = i & 1023;
    float v = Wv[i];
    int ntb = n >> 8, wc = (n >> 6) & 3, ntl = (n >> 5) & 1, nl = n & 31;
    int kit = k >> 6, ks = (k >> 4) & 3, lg = (k >> 3) & 1, j = k & 7;
    int lane = lg * 32 + nl;
    BP[((((((ntb * 16 + kit) * 4 + wc) * 4 + ks) * 2 + ntl) * 64 + lane) * 8) + j] = (f16)v;
}

// ---------------------------------------------------------------------------
// hq = query @ Wq + bq  (fp32). K split 4 ways, atomicAdd combine.
__global__ void hq_kernel(const float* __restrict__ query, const float* __restrict__ Wq,
                          const float* __restrict__ bq, float* __restrict__ hq) {
    int b = blockIdx.y;
    int h = (blockIdx.x & 3) * 256 + threadIdx.x;
    int v0 = (blockIdx.x >> 2) * 256;
    float acc = 0.f;
#pragma unroll 8
    for (int v = 0; v < 256; ++v)
        acc += query[b * 1024 + v0 + v] * Wq[(v0 + v) * 1024 + h];
    if (v0 == 0) acc += bq[h];
    atomicAdd(&hq[b * 1024 + h], acc);
}

// ---------------------------------------------------------------------------
// Fused 64x256x(K=1024) GEMM tile + tanh(hq+hv)·w row-reduction.
// Round-14 skeleton at BK=64: 16 epochs (HALF the barriers/lgkm drains).
// B: half-split reg buffers bvA(ks01)/bvB(ks23), each reloaded for epoch e+1
//    immediately after its last MFMA of epoch e -> >half-epoch L2 cover,
//    no swap logic. A: 4xfloat4 issued at epoch start, cvt+ds_write at epoch
//    end (full-epoch HBM cover), frag-ordered LDS dbuf 2x8KB, conflict-free
//    l*16 reads. vmcnt NEVER drained (compiler-auto waits only).
// 4 waves (256 thr), wave tile 64x64, launch_bounds(256,3): ~144 regs <= 170,
// 3 independent blocks/CU.
__launch_bounds__(256, 3)
__global__ void fused_main(const float* __restrict__ value, const f16* __restrict__ BP,
                           const float* __restrict__ hq, const float* __restrict__ wvec,
                           float* __restrict__ lpart) {
    __shared__ char A0[8192];                  // frag-ordered [mt(2)][ks(4)][lane][j]
    __shared__ char A1[8192];
    __shared__ float part[256];                // [wc(4)][row(64)]

    int bid = blockIdx.x;
    int tile = (bid & 7) * 512 + (bid >> 3);   // XCD swizzle (4096 % 8 == 0)
    int Mt = tile >> 2, ntb = tile & 3;        // 4 ntb of one Mt co-XCD
    int m0 = Mt << 6;                          // 64 rows
    int b = m0 >> 11, s0 = m0 & 2047;

    int tid = threadIdx.x;
    int wc = tid >> 6, l = tid & 63;
    int l31 = l & 31, lg = l >> 5;

    // ---- A staging: thread covers row tid>>2 (0..63), 16 floats at (tid&3)*16
    // (exactly one ks-slice = tid&3; two j-groups lg=0,1)
    int arow = tid >> 2;
    const float* aga = value + (size_t)(m0 + arow) * 1024 + (tid & 3) * 16;
    int aw0 = ((arow >> 5) * 4 + (tid & 3)) * 1024 + ((arow & 31) << 4);
    int aw1 = aw0 + 512;                       // lg=1 -> lane+32 -> +32*16B

    // ---- B per-wave base; epoch e chunk (8 KB) at + e*32768; halves at +0/+4096
    const char* bg = (const char*)BP + (size_t)ntb * 524288 + (size_t)wc * 8192
                   + (size_t)l * 16;

    // ---- A frag read offsets (conflict-free lane*16): mt*4096 + ks*1024
    int a_m0 = l * 16;
    int a_m1 = 4096 + l * 16;

    const f32x16 fzero = {};
    f32x16 acc[2][2];
#pragma unroll
    for (int mt = 0; mt < 2; ++mt)
#pragma unroll
        for (int nt = 0; nt < 2; ++nt) acc[mt][nt] = fzero;

    f16x8 bvA[4], bvB[4];                      // B half-epoch buffers (ks01 / ks23)
    float4 ar0, ar1, ar2, ar3;                 // A staging (1-epoch cover)

#define COMPUTE_HALF(Ab, BV, kso) do { \
        f16x8 a00 = *(const f16x8*)((Ab) + a_m0 + ((kso) + 0) * 1024); \
        f16x8 a10 = *(const f16x8*)((Ab) + a_m1 + ((kso) + 0) * 1024); \
        f16x8 a01 = *(const f16x8*)((Ab) + a_m0 + ((kso) + 1) * 1024); \
        f16x8 a11 = *(const f16x8*)((Ab) + a_m1 + ((kso) + 1) * 1024); \
        __builtin_amdgcn_s_setprio(1); \
        acc[0][0] = __builtin_amdgcn_mfma_f32_32x32x16_f16(a00, (BV)[0], acc[0][0], 0, 0, 0); \
        acc[0][1] = __builtin_amdgcn_mfma_f32_32x32x16_f16(a00, (BV)[1], acc[0][1], 0, 0, 0); \
        acc[1][0] = __builtin_amdgcn_mfma_f32_32x32x16_f16(a10, (BV)[0], acc[1][0], 0, 0, 0); \
        acc[1][1] = __builtin_amdgcn_mfma_f32_32x32x16_f16(a10, (BV)[1], acc[1][1], 0, 0, 0); \
        acc[0][0] = __builtin_amdgcn_mfma_f32_32x32x16_f16(a01, (BV)[2], acc[0][0], 0, 0, 0); \
        acc[0][1] = __builtin_amdgcn_mfma_f32_32x32x16_f16(a01, (BV)[3], acc[0][1], 0, 0, 0); \
        acc[1][0] = __builtin_amdgcn_mfma_f32_32x32x16_f16(a11, (BV)[2], acc[1][0], 0, 0, 0); \
        acc[1][1] = __builtin_amdgcn_mfma_f32_32x32x16_f16(a11, (BV)[3], acc[1][1], 0, 0, 0); \
        __builtin_amdgcn_s_setprio(0); \
    } while (0)

#define LOADB(BV, e, half) do { \
        const char* bt_ = bg + (size_t)(e) * 32768 + (half) * 4096; \
        (BV)[0] = *(const f16x8*)(bt_); \
        (BV)[1] = *(const f16x8*)(bt_ + 1024); \
        (BV)[2] = *(const f16x8*)(bt_ + 2048); \
        (BV)[3] = *(const f16x8*)(bt_ + 3072); \
    } while (0)

    // ---- prologue: A(0)->A0; B(0) both halves
    {
        const float4* ap = (const float4*)aga;
        ar0 = ap[0]; ar1 = ap[1]; ar2 = ap[2]; ar3 = ap[3];
        write_a16(A0, aw0, ar0, ar1);
        write_a16(A0, aw1, ar2, ar3);
        LOADB(bvA, 0, 0);
        LOADB(bvB, 0, 1);
        asm volatile("s_waitcnt lgkmcnt(0)" ::: "memory");
        __builtin_amdgcn_s_barrier();
    }

    // ---- main loop: 16 epochs of BK=64; ONE lgkm(0)+barrier per epoch,
    // vmcnt never drained (every load has >= half-epoch of cover).
#pragma unroll 1
    for (int e = 0; e < 16; ++e) {
        char* Ac = (e & 1) ? A1 : A0;
        char* An = (e & 1) ? A0 : A1;
        int en = (e < 15) ? e + 1 : 15;        // clamped dummies at tail (unused)

        // issue A(e+1) (full-epoch cover)
        const float4* ap = (const float4*)(aga + en * 64);
        ar0 = ap[0]; ar1 = ap[1]; ar2 = ap[2]; ar3 = ap[3];

        COMPUTE_HALF(Ac, bvA, 0);              // ks 0,1
        LOADB(bvA, en, 0);                     // B(e+1, ks01): cover = ks23+barrier
        COMPUTE_HALF(Ac, bvB, 2);              // ks 2,3
        LOADB(bvB, en, 1);                     // B(e+1, ks23): cover = tail+ks01

        write_a16(An, aw0, ar0, ar1);          // cvt + stage A(e+1)
        write_a16(An, aw1, ar2, ar3);
        asm volatile("s_waitcnt lgkmcnt(0)" ::: "memory");
        __builtin_amdgcn_s_barrier();
    }
#undef COMPUTE_HALF
#undef LOADB

    // ---- epilogue: t = tanh(hq + hv) * w, pair-folded col reduction
    int h0 = ntb * 256 + wc * 64 + l31;   // ntl = 0
    int h1 = h0 + 32;                     // ntl = 1
    float hq0 = hq[b * 1024 + h0], hq1 = hq[b * 1024 + h1];
    float w0 = wvec[h0], w1 = wvec[h1];

#pragma unroll
    for (int mt = 0; mt < 2; ++mt) {
#pragma unroll
        for (int i = 0; i < 8; ++i) {
            float pa = tanh_f(hq0 + acc[mt][0][2 * i]) * w0
                     + tanh_f(hq1 + acc[mt][1][2 * i]) * w1;
            float pb = tanh_f(hq0 + acc[mt][0][2 * i + 1]) * w0
                     + tanh_f(hq1 + acc[mt][1][2 * i + 1]) * w1;
            float ea = __shfl_xor(pa, 1), eb = __shfl_xor(pb, 1);
            float g = (l & 1) ? (pb + eb) : (pa + ea);
            g += __shfl_xor(g, 2); g += __shfl_xor(g, 4);
            g += __shfl_xor(g, 8); g += __shfl_xor(g, 16);
            if (l31 < 2) {
                int r = 2 * i + (l31 & 1);
                int row = mt * 32 + (r & 3) + ((r >> 2) << 3) + (lg << 2);
                part[wc * 64 + row] = g;
            }
        }
    }
    __syncthreads();
    if (tid < 64) {
        float s = part[tid] + part[64 + tid] + part[128 + tid] + part[192 + tid];
        lpart[((size_t)ntb * 32 + b) * 2048 + s0 + tid] = s;
    }
}

// ---------------------------------------------------------------------------
// Masked softmax over S=2048 per b, summing the 4 N-block logit partials.
__global__ void softmax_kernel(const float* __restrict__ lp, const int* __restrict__ mask,
                               float* __restrict__ out) {
    __shared__ float redm[16];
    __shared__ float reds[16];
    const int P = 32 * 2048;
    int b = blockIdx.x, t = threadIdx.x;
    int wid = t >> 6, lane = t & 63;
    int i0 = b * 2048 + t, i1 = i0 + 1024;
    float l0 = lp[i0] + lp[P + i0] + lp[2 * P + i0] + lp[3 * P + i0];
    float l1 = lp[i1] + lp[P + i1] + lp[2 * P + i1] + lp[3 * P + i1];
    float a0 = mask[i0] ? l0 : -1e9f;
    float a1 = mask[i1] ? l1 : -1e9f;
    float mx = fmaxf(a0, a1);
#pragma unroll
    for (int off = 1; off < 64; off <<= 1) mx = fmaxf(mx, __shfl_xor(mx, off));
    if (lane == 0) redm[wid] = mx;
    __syncthreads();
    mx = redm[0];
#pragma unroll
    for (int i = 1; i < 16; ++i) mx = fmaxf(mx, redm[i]);
    float e0 = __expf(a0 - mx), e1 = __expf(a1 - mx);
    float s = e0 + e1;
#pragma unroll
    for (int off = 1; off < 64; off <<= 1) s += __shfl_xor(s, off);
    if (lane == 0) reds[wid] = s;
    __syncthreads();
    float tot = 0.f;
#pragma unroll
    for (int i = 0; i < 16; ++i) tot += reds[i];
    float inv = 1.0f / tot;
    out[b * 2048 + t] = e0 * inv;
    out[b * 2048 + 1024 + t] = e1 * inv;
}

// ---------------------------------------------------------------------------
extern "C" void kernel_launch(void* const* d_in, const int* in_sizes, int n_in,
                              void* d_out, int out_size, void* d_ws, size_t ws_size,
                              hipStream_t stream) {
    const float* query = (const float*)d_in[0];
    const float* value = (const float*)d_in[1];
    const int*   mask  = (const int*)d_in[2];
    const float* Wq    = (const float*)d_in[3];
    const float* bq    = (const float*)d_in[4];
    const float* Wv    = (const float*)d_in[5];
    const float* wv    = (const float*)d_in[6];

    char* ws = (char*)d_ws;
    f16*   BP    = (f16*)(ws + WS_BP);
    float* hq    = (float*)(ws + WS_HQ);
    float* lpart = (float*)(ws + WS_LP);
    float* out   = (float*)d_out;

    (void)hipMemsetAsync(hq, 0, BB * HH * sizeof(float), stream);
    pack_wv<<<(KK * HH) / 256, 256, 0, stream>>>(Wv, BP);
    hq_kernel<<<dim3(16, BB), 256, 0, stream>>>(query, Wq, bq, hq);
    fused_main<<<4096, 256, 0, stream>>>(value, BP, hq, wv, lpart);
    softmax_kernel<<<BB, 1024, 0, stream>>>(lpart, mask, out);
}